// Round 1
// baseline (202.834 us; speedup 1.0000x reference)
//
#include <hip/hip_runtime.h>

// B=2, S=2048, H=1024, NH=16, HD=64
// Reference reshape [B,S,H]->[B,NH,S,HD] is a VIEW: head n = flat chunk
// [n*S*HD, (n+1)*S*HD) per batch, i.e. a [2048,64] row-major block.
// out[b,q,n*64+d] = softmax_k(Q_n[q,:]·K_n[k,:]/8) @ V_n[k,d]

typedef short s16x8 __attribute__((ext_vector_type(8)));
typedef float f32x4 __attribute__((ext_vector_type(4)));

#define MFMA16(a, b, c) __builtin_amdgcn_mfma_f32_16x16x32_bf16((a), (b), (c), 0, 0, 0)

__device__ __forceinline__ short f2bf(float f) {
  // round-to-nearest-even fp32 -> bf16 (inputs are normal numbers)
  unsigned u = __builtin_bit_cast(unsigned, f);
  u = (u + 0x7fffu + ((u >> 16) & 1u)) >> 16;
  return (short)u;
}

struct ProjArgs {
  const float* X[3];
  const float* W[3];
  const float* Bv[3];
  short* Y[3];
  float scale[3];
};

// ---------------- Kernel 1: Y[z] = bf16((X[z] @ W[z]^T + b[z]) * scale[z])
// M=4096, N=1024, K=1024.  W is [N,K] row-major (torch Linear weight) -> B^T GEMM.
#define PBM 128
#define PBN 128
#define PBK 32
#define PLD (PBK + 8)  // padded leading dim in shorts (40)

__global__ __launch_bounds__(256) void qkv_proj_kernel(ProjArgs args) {
  const int z = blockIdx.z;
  const float* __restrict__ X = args.X[z];
  const float* __restrict__ W = args.W[z];
  const float* __restrict__ Bv = args.Bv[z];
  short* __restrict__ Y = args.Y[z];
  const float scale = args.scale[z];

  __shared__ __align__(16) short As[PBM][PLD];
  __shared__ __align__(16) short Bs[PBN][PLD];

  const int tid = threadIdx.x;
  const int lane = tid & 63;
  const int wave = tid >> 6;
  const int m0 = blockIdx.y * PBM;
  const int n0 = blockIdx.x * PBN;
  const int moff = (wave >> 1) * 64;
  const int noff = (wave & 1) * 64;
  const int fr = lane & 15;        // fragment row/col within 16
  const int fk = (lane >> 4) * 8;  // k offset within 32

  const int srow = tid >> 1;         // 0..127 staging row
  const int scol = (tid & 1) * 16;   // 0 or 16

  f32x4 acc[4][4] = {};

  const float* ap = X + (size_t)(m0 + srow) * 1024 + scol;
  const float* bp = W + (size_t)(n0 + srow) * 1024 + scol;

  for (int k0 = 0; k0 < 1024; k0 += PBK) {
    f32x4 a0 = *(const f32x4*)(ap + k0);
    f32x4 a1 = *(const f32x4*)(ap + k0 + 4);
    f32x4 a2 = *(const f32x4*)(ap + k0 + 8);
    f32x4 a3 = *(const f32x4*)(ap + k0 + 12);
    f32x4 b0 = *(const f32x4*)(bp + k0);
    f32x4 b1 = *(const f32x4*)(bp + k0 + 4);
    f32x4 b2 = *(const f32x4*)(bp + k0 + 8);
    f32x4 b3 = *(const f32x4*)(bp + k0 + 12);

    s16x8 sa0, sa1, sb0, sb1;
#pragma unroll
    for (int j = 0; j < 4; ++j) {
      sa0[j] = f2bf(a0[j]); sa0[j + 4] = f2bf(a1[j]);
      sa1[j] = f2bf(a2[j]); sa1[j + 4] = f2bf(a3[j]);
      sb0[j] = f2bf(b0[j]); sb0[j + 4] = f2bf(b1[j]);
      sb1[j] = f2bf(b2[j]); sb1[j + 4] = f2bf(b3[j]);
    }

    __syncthreads();  // previous-iter readers done before overwrite
    *(s16x8*)&As[srow][scol]     = sa0;
    *(s16x8*)&As[srow][scol + 8] = sa1;
    *(s16x8*)&Bs[srow][scol]     = sb0;
    *(s16x8*)&Bs[srow][scol + 8] = sb1;
    __syncthreads();

    s16x8 af[4], bfm[4];
#pragma unroll
    for (int i = 0; i < 4; ++i) af[i] = *(const s16x8*)&As[moff + i * 16 + fr][fk];
#pragma unroll
    for (int j = 0; j < 4; ++j) bfm[j] = *(const s16x8*)&Bs[noff + j * 16 + fr][fk];
#pragma unroll
    for (int i = 0; i < 4; ++i)
#pragma unroll
      for (int j = 0; j < 4; ++j)
        acc[i][j] = MFMA16(af[i], bfm[j], acc[i][j]);
  }

  // epilogue: C/D layout col = lane&15, row = (lane>>4)*4 + reg (m89-verified)
#pragma unroll
  for (int j = 0; j < 4; ++j) {
    const int col = n0 + noff + j * 16 + fr;
    const float bias = Bv[col];
#pragma unroll
    for (int i = 0; i < 4; ++i) {
      const int rowb = m0 + moff + i * 16 + (lane >> 4) * 4;
#pragma unroll
      for (int r = 0; r < 4; ++r) {
        Y[(size_t)(rowb + r) * 1024 + col] = f2bf((acc[i][j][r] + bias) * scale);
      }
    }
  }
}

// ---------------- Kernel 2: flash attention over 32 [2048,64] heads
#define QBLK 128
#define KVB 64
#define ALD 72  // 64 + 8 pad, shorts

__global__ __launch_bounds__(512) void attn_kernel(
    const short* __restrict__ Qb, const short* __restrict__ Kb,
    const short* __restrict__ Vb, float* __restrict__ out) {
  const int qb = blockIdx.x;    // 0..15 q tile
  const int head = blockIdx.y;  // 0..15
  const int bz = blockIdx.z;    // 0..1

  const size_t hb = (size_t)bz * (2048 * 1024) + (size_t)head * (2048 * 64);
  const short* Qh = Qb + hb;
  const short* Kh = Kb + hb;
  const short* Vh = Vb + hb;

  __shared__ __align__(16) short Qs[QBLK][ALD];
  __shared__ __align__(16) short Ks[KVB][ALD];
  __shared__ __align__(16) short Vts[64][ALD];   // V transposed: [d][k]
  __shared__ __align__(16) short Ps[QBLK][ALD];  // P, per-wave 16-row slabs

  const int tid = threadIdx.x;
  const int lane = tid & 63;
  const int wave = tid >> 6;  // 0..7, owns q rows [wave*16, wave*16+16)
  const int fr = lane & 15;
  const int fk = (lane >> 4) * 8;
  const int qlds = wave * 16;

  // stage Q tile [128][64]
  {
    const int r = tid >> 2;
    const int c = (tid & 3) * 16;
    const short* src = Qh + (size_t)(qb * QBLK + r) * 64 + c;
    *(s16x8*)&Qs[r][c]     = *(const s16x8*)src;
    *(s16x8*)&Qs[r][c + 8] = *(const s16x8*)(src + 8);
  }
  __syncthreads();

  // A-operand frags of Q are loop-invariant
  const s16x8 aq0 = *(const s16x8*)&Qs[qlds + fr][fk];
  const s16x8 aq1 = *(const s16x8*)&Qs[qlds + fr][32 + fk];

  float m_st[4], l_st[4];
  f32x4 acc[4] = {};  // O accumulator: [d-chunk][reg]
#pragma unroll
  for (int r = 0; r < 4; ++r) { m_st[r] = -1e30f; l_st[r] = 0.f; }

  const int sr = tid >> 3;       // 0..63 staging row
  const int sc = (tid & 7) * 8;  // 0..56

  for (int kv0 = 0; kv0 < 2048; kv0 += KVB) {
    // stage K [64][64] natural, V transposed
    s16x8 kvec = *(const s16x8*)(Kh + (size_t)(kv0 + sr) * 64 + sc);
    s16x8 vvec = *(const s16x8*)(Vh + (size_t)(kv0 + sr) * 64 + sc);
    *(s16x8*)&Ks[sr][sc] = kvec;
#pragma unroll
    for (int j = 0; j < 8; ++j) Vts[sc + j][sr] = vvec[j];
    __syncthreads();

    // E = (Q/8) K^T   (scale pre-folded into Q)
    f32x4 e[4];
#pragma unroll
    for (int f = 0; f < 4; ++f) {
      s16x8 bk0 = *(const s16x8*)&Ks[f * 16 + fr][fk];
      s16x8 bk1 = *(const s16x8*)&Ks[f * 16 + fr][32 + fk];
      f32x4 zz = {};
      zz = MFMA16(aq0, bk0, zz);
      e[f] = MFMA16(aq1, bk1, zz);
    }

    // online softmax; E row = (lane>>4)*4 + r, col = f*16 + fr
#pragma unroll
    for (int r = 0; r < 4; ++r) {
      float t = fmaxf(fmaxf(e[0][r], e[1][r]), fmaxf(e[2][r], e[3][r]));
#pragma unroll
      for (int off = 8; off >= 1; off >>= 1) t = fmaxf(t, __shfl_xor(t, off));
      const float mnew = fmaxf(m_st[r], t);
      const float corr = __expf(m_st[r] - mnew);
      m_st[r] = mnew;
      const float p0 = __expf(e[0][r] - mnew);
      const float p1 = __expf(e[1][r] - mnew);
      const float p2 = __expf(e[2][r] - mnew);
      const float p3 = __expf(e[3][r] - mnew);
      float s = (p0 + p1) + (p2 + p3);
#pragma unroll
      for (int off = 8; off >= 1; off >>= 1) s += __shfl_xor(s, off);
      l_st[r] = l_st[r] * corr + s;
#pragma unroll
      for (int d = 0; d < 4; ++d) acc[d][r] *= corr;
      const int prow = qlds + (lane >> 4) * 4 + r;
      Ps[prow][fr]      = f2bf(p0);
      Ps[prow][16 + fr] = f2bf(p1);
      Ps[prow][32 + fr] = f2bf(p2);
      Ps[prow][48 + fr] = f2bf(p3);
    }

    // O += P @ V  (P via per-wave LDS round-trip; V^T gives contiguous B frags)
    s16x8 pa0 = *(const s16x8*)&Ps[qlds + fr][fk];
    s16x8 pa1 = *(const s16x8*)&Ps[qlds + fr][32 + fk];
#pragma unroll
    for (int d = 0; d < 4; ++d) {
      s16x8 bv0 = *(const s16x8*)&Vts[d * 16 + fr][fk];
      s16x8 bv1 = *(const s16x8*)&Vts[d * 16 + fr][32 + fk];
      acc[d] = MFMA16(pa1, bv1, MFMA16(pa0, bv0, acc[d]));
    }
    __syncthreads();  // protect K/V/LDS restage
  }

  // epilogue: out[b, q, head*64 + d]
#pragma unroll
  for (int r = 0; r < 4; ++r) {
    const float inv = 1.0f / l_st[r];
    const int q = qb * QBLK + qlds + (lane >> 4) * 4 + r;
    float* op = out + ((size_t)bz * 2048 + q) * 1024 + head * 64;
#pragma unroll
    for (int d = 0; d < 4; ++d) op[d * 16 + fr] = acc[d][r] * inv;
  }
}

extern "C" void kernel_launch(void* const* d_in, const int* in_sizes, int n_in,
                              void* d_out, int out_size, void* d_ws, size_t ws_size,
                              hipStream_t stream) {
  const float* query = (const float*)d_in[0];
  const float* key   = (const float*)d_in[1];
  const float* value = (const float*)d_in[2];
  const float* Wq = (const float*)d_in[3];
  const float* bq = (const float*)d_in[4];
  const float* Wk = (const float*)d_in[5];
  const float* bk = (const float*)d_in[6];
  const float* Wv = (const float*)d_in[7];
  const float* bv = (const float*)d_in[8];
  float* out = (float*)d_out;

  short* Qw = (short*)d_ws;                       // [4096][1024] bf16, pre-scaled by 1/8
  short* Kw = Qw + (size_t)4096 * 1024;
  short* Vw = Kw + (size_t)4096 * 1024;

  ProjArgs pa;
  pa.X[0] = query; pa.X[1] = key; pa.X[2] = value;
  pa.W[0] = Wq; pa.W[1] = Wk; pa.W[2] = Wv;
  pa.Bv[0] = bq; pa.Bv[1] = bk; pa.Bv[2] = bv;
  pa.Y[0] = Qw; pa.Y[1] = Kw; pa.Y[2] = Vw;
  pa.scale[0] = 0.125f; pa.scale[1] = 1.0f; pa.scale[2] = 1.0f;

  qkv_proj_kernel<<<dim3(1024 / PBN, 4096 / PBM, 3), 256, 0, stream>>>(pa);
  attn_kernel<<<dim3(2048 / QBLK, 16, 2), 512, 0, stream>>>(Qw, Kw, Vw, out);
}

// Round 2
// 202.526 us; speedup vs baseline: 1.0015x; 1.0015x over previous
//
#include <hip/hip_runtime.h>

// B=2, S=2048, H=1024, NH=16, HD=64
// Reference reshape [B,S,H]->[B,NH,S,HD] is a VIEW: head n = flat chunk
// [n*S*HD, (n+1)*S*HD) per batch, i.e. a [2048,64] row-major block.
// out[b,q,n*64+d] = softmax_k(Q_n[q,:]·K_n[k,:]/8) @ V_n[k,d]

typedef short s16x8 __attribute__((ext_vector_type(8)));
typedef float f32x4 __attribute__((ext_vector_type(4)));

#define MFMA16(a, b, c) __builtin_amdgcn_mfma_f32_16x16x32_bf16((a), (b), (c), 0, 0, 0)

__device__ __forceinline__ short f2bf(float f) {
  // round-to-nearest-even fp32 -> bf16 (inputs are normal numbers)
  unsigned u = __builtin_bit_cast(unsigned, f);
  u = (u + 0x7fffu + ((u >> 16) & 1u)) >> 16;
  return (short)u;
}

struct ProjArgs {
  const float* X[3];
  const float* W[3];
  const float* Bv[3];
  short* Y[3];
  float scale[3];
};

// ---------------- Kernel 1: Y[z] = bf16((X[z] @ W[z]^T + b[z]) * scale[z])
// M=4096, N=1024, K=1024.  W is [N,K] row-major (torch Linear weight) -> B^T GEMM.
#define PBM 128
#define PBN 128
#define PBK 32
#define PLD (PBK + 8)  // padded leading dim in shorts (40)

__global__ __launch_bounds__(256) void qkv_proj_kernel(ProjArgs args) {
  const int z = blockIdx.z;
  const float* __restrict__ X = args.X[z];
  const float* __restrict__ W = args.W[z];
  const float* __restrict__ Bv = args.Bv[z];
  short* __restrict__ Y = args.Y[z];
  const float scale = args.scale[z];

  __shared__ __align__(16) short As[PBM][PLD];
  __shared__ __align__(16) short Bs[PBN][PLD];

  const int tid = threadIdx.x;
  const int lane = tid & 63;
  const int wave = tid >> 6;
  const int m0 = blockIdx.y * PBM;
  const int n0 = blockIdx.x * PBN;
  const int moff = (wave >> 1) * 64;
  const int noff = (wave & 1) * 64;
  const int fr = lane & 15;        // fragment row/col within 16
  const int fk = (lane >> 4) * 8;  // k offset within 32

  const int srow = tid >> 1;         // 0..127 staging row
  const int scol = (tid & 1) * 16;   // 0 or 16

  f32x4 acc[4][4] = {};

  const float* ap = X + (size_t)(m0 + srow) * 1024 + scol;
  const float* bp = W + (size_t)(n0 + srow) * 1024 + scol;

  for (int k0 = 0; k0 < 1024; k0 += PBK) {
    f32x4 a0 = *(const f32x4*)(ap + k0);
    f32x4 a1 = *(const f32x4*)(ap + k0 + 4);
    f32x4 a2 = *(const f32x4*)(ap + k0 + 8);
    f32x4 a3 = *(const f32x4*)(ap + k0 + 12);
    f32x4 b0 = *(const f32x4*)(bp + k0);
    f32x4 b1 = *(const f32x4*)(bp + k0 + 4);
    f32x4 b2 = *(const f32x4*)(bp + k0 + 8);
    f32x4 b3 = *(const f32x4*)(bp + k0 + 12);

    s16x8 sa0, sa1, sb0, sb1;
#pragma unroll
    for (int j = 0; j < 4; ++j) {
      sa0[j] = f2bf(a0[j]); sa0[j + 4] = f2bf(a1[j]);
      sa1[j] = f2bf(a2[j]); sa1[j + 4] = f2bf(a3[j]);
      sb0[j] = f2bf(b0[j]); sb0[j + 4] = f2bf(b1[j]);
      sb1[j] = f2bf(b2[j]); sb1[j + 4] = f2bf(b3[j]);
    }

    __syncthreads();  // previous-iter readers done before overwrite
    *(s16x8*)&As[srow][scol]     = sa0;
    *(s16x8*)&As[srow][scol + 8] = sa1;
    *(s16x8*)&Bs[srow][scol]     = sb0;
    *(s16x8*)&Bs[srow][scol + 8] = sb1;
    __syncthreads();

    s16x8 af[4], bfm[4];
#pragma unroll
    for (int i = 0; i < 4; ++i) af[i] = *(const s16x8*)&As[moff + i * 16 + fr][fk];
#pragma unroll
    for (int j = 0; j < 4; ++j) bfm[j] = *(const s16x8*)&Bs[noff + j * 16 + fr][fk];
#pragma unroll
    for (int i = 0; i < 4; ++i)
#pragma unroll
      for (int j = 0; j < 4; ++j)
        acc[i][j] = MFMA16(af[i], bfm[j], acc[i][j]);
  }

  // epilogue: C/D layout col = lane&15, row = (lane>>4)*4 + reg (m89-verified)
#pragma unroll
  for (int j = 0; j < 4; ++j) {
    const int col = n0 + noff + j * 16 + fr;
    const float bias = Bv[col];
#pragma unroll
    for (int i = 0; i < 4; ++i) {
      const int rowb = m0 + moff + i * 16 + (lane >> 4) * 4;
#pragma unroll
      for (int r = 0; r < 4; ++r) {
        Y[(size_t)(rowb + r) * 1024 + col] = f2bf((acc[i][j][r] + bias) * scale);
      }
    }
  }
}

// ---------------- Kernel 2: flash attention over 32 [2048,64] heads
#define QBLK 128
#define KVB 64
#define ALD 72  // 64 + 8 pad, shorts

__global__ __launch_bounds__(512) void attn_kernel(
    const short* __restrict__ Qb, const short* __restrict__ Kb,
    const short* __restrict__ Vb, float* __restrict__ out) {
  const int qb = blockIdx.x;    // 0..15 q tile
  const int head = blockIdx.y;  // 0..15
  const int bz = blockIdx.z;    // 0..1

  const size_t hb = (size_t)bz * (2048 * 1024) + (size_t)head * (2048 * 64);
  const short* Qh = Qb + hb;
  const short* Kh = Kb + hb;
  const short* Vh = Vb + hb;

  __shared__ __align__(16) short Qs[QBLK][ALD];
  __shared__ __align__(16) short Ks[KVB][ALD];
  __shared__ __align__(16) short Vts[64][ALD];   // V transposed: [d][k]
  __shared__ __align__(16) short Ps[QBLK][ALD];  // P, per-wave 16-row slabs

  const int tid = threadIdx.x;
  const int lane = tid & 63;
  const int wave = tid >> 6;  // 0..7, owns q rows [wave*16, wave*16+16)
  const int fr = lane & 15;
  const int fk = (lane >> 4) * 8;
  const int qlds = wave * 16;

  // stage Q tile [128][64]
  {
    const int r = tid >> 2;
    const int c = (tid & 3) * 16;
    const short* src = Qh + (size_t)(qb * QBLK + r) * 64 + c;
    *(s16x8*)&Qs[r][c]     = *(const s16x8*)src;
    *(s16x8*)&Qs[r][c + 8] = *(const s16x8*)(src + 8);
  }
  __syncthreads();

  // A-operand frags of Q are loop-invariant
  const s16x8 aq0 = *(const s16x8*)&Qs[qlds + fr][fk];
  const s16x8 aq1 = *(const s16x8*)&Qs[qlds + fr][32 + fk];

  float m_st[4], l_st[4];
  f32x4 acc[4] = {};  // O accumulator: [d-chunk][reg]
#pragma unroll
  for (int r = 0; r < 4; ++r) { m_st[r] = -1e30f; l_st[r] = 0.f; }

  const int sr = tid >> 3;       // 0..63 staging row
  const int sc = (tid & 7) * 8;  // 0..56

  for (int kv0 = 0; kv0 < 2048; kv0 += KVB) {
    // stage K [64][64] natural, V transposed
    s16x8 kvec = *(const s16x8*)(Kh + (size_t)(kv0 + sr) * 64 + sc);
    s16x8 vvec = *(const s16x8*)(Vh + (size_t)(kv0 + sr) * 64 + sc);
    *(s16x8*)&Ks[sr][sc] = kvec;
#pragma unroll
    for (int j = 0; j < 8; ++j) Vts[sc + j][sr] = vvec[j];
    __syncthreads();

    // E = (Q/8) K^T   (scale pre-folded into Q)
    f32x4 e[4];
#pragma unroll
    for (int f = 0; f < 4; ++f) {
      s16x8 bk0 = *(const s16x8*)&Ks[f * 16 + fr][fk];
      s16x8 bk1 = *(const s16x8*)&Ks[f * 16 + fr][32 + fk];
      f32x4 zz = {};
      zz = MFMA16(aq0, bk0, zz);
      e[f] = MFMA16(aq1, bk1, zz);
    }

    // online softmax; E row = (lane>>4)*4 + r, col = f*16 + fr
#pragma unroll
    for (int r = 0; r < 4; ++r) {
      float t = fmaxf(fmaxf(e[0][r], e[1][r]), fmaxf(e[2][r], e[3][r]));
#pragma unroll
      for (int off = 8; off >= 1; off >>= 1) t = fmaxf(t, __shfl_xor(t, off));
      const float mnew = fmaxf(m_st[r], t);
      const float corr = __expf(m_st[r] - mnew);
      m_st[r] = mnew;
      const float p0 = __expf(e[0][r] - mnew);
      const float p1 = __expf(e[1][r] - mnew);
      const float p2 = __expf(e[2][r] - mnew);
      const float p3 = __expf(e[3][r] - mnew);
      float s = (p0 + p1) + (p2 + p3);
#pragma unroll
      for (int off = 8; off >= 1; off >>= 1) s += __shfl_xor(s, off);
      l_st[r] = l_st[r] * corr + s;
#pragma unroll
      for (int d = 0; d < 4; ++d) acc[d][r] *= corr;
      const int prow = qlds + (lane >> 4) * 4 + r;
      Ps[prow][fr]      = f2bf(p0);
      Ps[prow][16 + fr] = f2bf(p1);
      Ps[prow][32 + fr] = f2bf(p2);
      Ps[prow][48 + fr] = f2bf(p3);
    }

    // O += P @ V  (P via per-wave LDS round-trip; V^T gives contiguous B frags)
    s16x8 pa0 = *(const s16x8*)&Ps[qlds + fr][fk];
    s16x8 pa1 = *(const s16x8*)&Ps[qlds + fr][32 + fk];
#pragma unroll
    for (int d = 0; d < 4; ++d) {
      s16x8 bv0 = *(const s16x8*)&Vts[d * 16 + fr][fk];
      s16x8 bv1 = *(const s16x8*)&Vts[d * 16 + fr][32 + fk];
      acc[d] = MFMA16(pa1, bv1, MFMA16(pa0, bv0, acc[d]));
    }
    __syncthreads();  // protect K/V/LDS restage
  }

  // epilogue: out[b, q, head*64 + d]
#pragma unroll
  for (int r = 0; r < 4; ++r) {
    const float inv = 1.0f / l_st[r];
    const int q = qb * QBLK + qlds + (lane >> 4) * 4 + r;
    float* op = out + ((size_t)bz * 2048 + q) * 1024 + head * 64;
#pragma unroll
    for (int d = 0; d < 4; ++d) op[d * 16 + fr] = acc[d][r] * inv;
  }
}

extern "C" void kernel_launch(void* const* d_in, const int* in_sizes, int n_in,
                              void* d_out, int out_size, void* d_ws, size_t ws_size,
                              hipStream_t stream) {
  const float* query = (const float*)d_in[0];
  const float* key   = (const float*)d_in[1];
  const float* value = (const float*)d_in[2];
  const float* Wq = (const float*)d_in[3];
  const float* bq = (const float*)d_in[4];
  const float* Wk = (const float*)d_in[5];
  const float* bk = (const float*)d_in[6];
  const float* Wv = (const float*)d_in[7];
  const float* bv = (const float*)d_in[8];
  float* out = (float*)d_out;

  short* Qw = (short*)d_ws;                       // [4096][1024] bf16, pre-scaled by 1/8
  short* Kw = Qw + (size_t)4096 * 1024;
  short* Vw = Kw + (size_t)4096 * 1024;

  ProjArgs pa;
  pa.X[0] = query; pa.X[1] = key; pa.X[2] = value;
  pa.W[0] = Wq; pa.W[1] = Wk; pa.W[2] = Wv;
  pa.Bv[0] = bq; pa.Bv[1] = bk; pa.Bv[2] = bv;
  pa.Y[0] = Qw; pa.Y[1] = Kw; pa.Y[2] = Vw;
  pa.scale[0] = 0.125f; pa.scale[1] = 1.0f; pa.scale[2] = 1.0f;

  qkv_proj_kernel<<<dim3(1024 / PBN, 4096 / PBM, 3), 256, 0, stream>>>(pa);
  attn_kernel<<<dim3(2048 / QBLK, 16, 2), 512, 0, stream>>>(Qw, Kw, Vw, out);
}